// Round 5
// baseline (2079.598 us; speedup 1.0000x reference)
//
#include <hip/hip_runtime.h>

// GRU_54614804135975: 128-step GRU (B=1024,D=256,H=1024) + per-frame BatchNorm.
// Persistent kernel. R5 changes vs R4 (1705us gru, 2023us total):
//  * 256 blocks x 512 thr (1 block/CU, 8 waves = 2/SIMD), block tile 128x128.
//    4 output tiles of 64x64; each tile computed by a WAVE PAIR splitting K
//    (w<4: k 0..31 of each kt; w>=4: k 32..63), merged once per step via an
//    LDS f32 scratch. LDS traffic/step/CU: 2.34 MB -> 1.70 MB (reads
//    1.57->1.05, writes 0.77->0.52, +0.13 merge). LDS port was the wall
//    (R4: ~8.7us of 13.3us step); MFMA (4.1us) hides under it.
//  * Staging shared by 512 threads: per-thread staging instrs halve.
//  * Scratch overlays As[0..2]+Bs[2] (64KB); syncthreads after kt-loop
//    protects the overlay; pre-issued next-step B uses Bs[0..1] only.
//  * Exchange/barrier kept from R4 (proven): HH[t] SC1 write-through,
//    plain first-touch A reads, 32-slot flag array + ballot poll.
//  vmcnt (4-instr stages: A2+B2): steady wait vmcnt(4); t>=1 kt=0 waits
//  vmcnt(2) (FIFO [B0 B1 A0 A1], A0 done when <=2 left); last kt vmcnt(0);
//  tail drain vmcnt(4) ([HHstore B0 B1], store done when <=4 left).

#define DEVI __device__ __forceinline__

typedef __bf16 bf16x8 __attribute__((ext_vector_type(8)));
typedef float f32x4 __attribute__((ext_vector_type(4)));
typedef unsigned int u32x4 __attribute__((ext_vector_type(4)));

typedef __attribute__((address_space(1))) const unsigned int g_u32;
typedef __attribute__((address_space(3))) unsigned int l_u32;

DEVI unsigned short f2b(float f) {
  union { float f; unsigned u; } v; v.f = f;
  return (unsigned short)((v.u + 0x7fffu + ((v.u >> 16) & 1u)) >> 16);
}

DEVI void gl_lds16(const void* g, void* s) {          // normal (L2-cached)
  __builtin_amdgcn_global_load_lds((g_u32*)g, (l_u32*)s, 16, 0, 0);
}
DEVI void st16_sc1(void* p, u32x4 v) {                // SC1 write-through to L3
  asm volatile("global_store_dwordx4 %0, %1, off sc1"
               :: "v"((unsigned long long)(__SIZE_TYPE__)p), "v"(v) : "memory");
}

DEVI float sigm(float x) { return 1.0f / (1.0f + __expf(-x)); }
DEVI float tanh_f(float x) {
  float t = __expf(-2.0f * fabsf(x));
  float r = (1.0f - t) / (1.0f + t);
  return x >= 0.0f ? r : -r;
}

// ---------------- persistent GRU recurrence ----------------
// grid = 256 blocks x 512 threads, 1 block/CU (all co-resident; required for
// the intra-group spin barrier). h crosses blocks via SC1 stores to the L3
// coherence point + first-touch plain reads -> mapping-agnostic correctness.
__global__ __launch_bounds__(512, 2) void gru_persist(
    const unsigned short* __restrict__ XB,   // 1024x256 bf16 (step-0 A)
    const unsigned short* __restrict__ WP0,  // 4096x256 bf16 n-major permuted
    const unsigned short* __restrict__ WP,   // 4096x1024 bf16 n-major permuted
    const float* __restrict__ C0v,           // step-0 gate consts [4][1024]
    const float* __restrict__ CBv,           // steady-state gate consts
    const float* __restrict__ h0,            // 1024x1024 fp32
    unsigned short* __restrict__ HH,         // history: 128 x 1024x1024 bf16
    unsigned int* __restrict__ bar)          // flags [8 groups][32 blocks]
{
  // As: 3 x 8192 shorts (48KB) | Bs: 3 x 8192 (48KB) | Hs: 4096 (8KB)
  __shared__ __align__(16) unsigned short smem[53248];
  unsigned short* const Asb = smem;
  unsigned short* const Bsb = smem + 24576;
  unsigned short* const Hs  = smem + 49152;

  const int tid = threadIdx.x;
  const int w = tid >> 6, lane = tid & 63;
  const int tw = w & 3, kh = w >> 2;        // tile 0..3, K-half 0/1
  const int twr = tw >> 1, twc = tw & 1;    // 2x2 tile grid, 64x64 each
  const int srow = lane >> 3;
  const int schunk = (lane & 7) ^ srow;     // XOR chunk swizzle (staging src)
  const int l15 = lane & 15, lg = lane >> 4;
  // XCD remap: b&7 = XCD slot; per XCD: all 8 mb x 4 nb (B 1MB + A-frame
  // slices 2MB L2-resident; 4 same-mb sharers per A-line). Bijective.
  const int xb_ = blockIdx.x & 7, rb_ = blockIdx.x >> 3;     // rb_: 0..31
  const int mb = rb_ & 7;                                    // 0..7
  const int nb = xb_ | ((rb_ >> 3) << 3);                    // 0..31
  const int j = nb * 32 + twc * 16 + l15;

  // gate consts only consumed by lower (kh==0) waves
  float c0r = 0, c0z = 0, c0i = 0, c0h = 0, cbr = 0, cbz = 0, cbi = 0, cbh = 0;
  if (kh == 0) {
    c0r = C0v[j]; c0z = C0v[1024 + j]; c0i = C0v[2048 + j]; c0h = C0v[3072 + j];
    cbr = CBv[j]; cbz = CBv[1024 + j]; cbi = CBv[2048 + j]; cbh = CBv[3072 + j];
  }

  float hreg[4][4];   // lower waves only (rows twr*64+mi*16+lg*4+i, col j)
  if (kh == 0) {
#pragma unroll
    for (int mi = 0; mi < 4; ++mi)
#pragma unroll
      for (int i = 0; i < 4; ++i)
        hreg[mi][i] =
            h0[(size_t)(mb * 128 + twr * 64 + mi * 16 + lg * 4 + i) * 1024 + j];
  }

  // ---- hoisted invariant addressing ----
  // ds_read byte offsets: slot = (kh*4+lg) ^ (l15&7) (row bits 0..2 == l15&7)
  const int slot = ((kh << 2) | lg) ^ (l15 & 7);
  int offA[4], offB[4];
#pragma unroll
  for (int q = 0; q < 4; ++q) {
    offA[q] = (twr * 64 + q * 16 + l15) * 128 + slot * 16;
    offB[q] = (twc * 64 + q * 16 + l15) * 128 + slot * 16;
  }
  // staging source offsets (elements): steady K=1024, step-0 K=256
  const int offq0 = srow * 1024 + schunk * 8;
  const int offq1 = (8 + srow) * 1024 + schunk * 8;
  const int offp0 = srow * 256 + schunk * 8;
  const int offp1 = (8 + srow) * 256 + schunk * 8;
  const size_t arow_off = (size_t)(mb * 128 + w * 16) * 1024;
  const unsigned short* BrowS = WP + (size_t)(nb * 128 + w * 16) * 1024;
  const unsigned short* Arow0 = XB + (size_t)(mb * 128 + w * 16) * 256;
  const unsigned short* Brow0 = WP0 + (size_t)(nb * 128 + w * 16) * 256;
  // f32 scratch for K-split merge: tiles 0..2 over As, tile 3 over Bs[2]
  float* const scr = (float*)smem + (tw < 3 ? tw * 4096 : 20480);

// per-wave VMEM instr counts: each stage = A(2)+B(2) = 4 (vmcnt arithmetic).
#define STAGE0(KT, BUF)                                                       \
  gl_lds16(Brow0 + offp0 + (KT) * 64, (char*)Bsb + (BUF) * 16384 + (w * 16) * 128);     \
  gl_lds16(Brow0 + offp1 + (KT) * 64, (char*)Bsb + (BUF) * 16384 + (w * 16 + 8) * 128); \
  gl_lds16(Arow0 + offp0 + (KT) * 64, (char*)Asb + (BUF) * 16384 + (w * 16) * 128);     \
  gl_lds16(Arow0 + offp1 + (KT) * 64, (char*)Asb + (BUF) * 16384 + (w * 16 + 8) * 128);
#define SSTAGE_B(KT, BUF)                                                     \
  gl_lds16(BrowS + offq0 + (KT) * 64, (char*)Bsb + (BUF) * 16384 + (w * 16) * 128);     \
  gl_lds16(BrowS + offq1 + (KT) * 64, (char*)Bsb + (BUF) * 16384 + (w * 16 + 8) * 128);
#define SSTAGE_A(KT, BUF)                                                     \
  gl_lds16(ArowS + offq0 + (KT) * 64, (char*)Asb + (BUF) * 16384 + (w * 16) * 128);     \
  gl_lds16(ArowS + offq1 + (KT) * 64, (char*)Asb + (BUF) * 16384 + (w * 16 + 8) * 128);

  for (int t = 0; t < 128; ++t) {
    const bool first = (t == 0);
    const int iters = first ? 4 : 16;
    const unsigned short* ArowS = HH + (((size_t)(first ? 0 : t - 1)) << 20) + arow_off;

    f32x4 acc[4][4] = {};

    if (first) {           // fresh prologue: stages 0,1
      STAGE0(0, 0)
      STAGE0(1, 1)
    } else {               // B0,B1 pre-issued at end of prev step; A only
      SSTAGE_A(0, 0)
      SSTAGE_A(1, 1)
    }
    int cur = 0, pre = 2;
    for (int kt = 0; kt < iters; ++kt) {
      if (kt == 0) {
        if (first) asm volatile("s_waitcnt vmcnt(4)" ::: "memory");
        else       asm volatile("s_waitcnt vmcnt(2)" ::: "memory");
      } else if (kt == iters - 1) {
        asm volatile("s_waitcnt vmcnt(0)" ::: "memory");
      } else {               // exactly one full stage (4) may stay in flight
        asm volatile("s_waitcnt vmcnt(4)" ::: "memory");
      }
      __builtin_amdgcn_s_barrier();   // raw: all waves' stage-kt data in LDS;
                                      // also: all kt-1 LDS reads retired
      if (kt + 2 < iters) {
        if (first) { STAGE0(kt + 2, pre) }
        else       { SSTAGE_B(kt + 2, pre) SSTAGE_A(kt + 2, pre) }
      }
      __builtin_amdgcn_s_setprio(1);
      {
        bf16x8 a[4], b[4];
        const char* Ab = (const char*)Asb + cur * 16384;
        const char* Bb = (const char*)Bsb + cur * 16384;
#pragma unroll
        for (int mi = 0; mi < 4; ++mi) a[mi] = *(const bf16x8*)(Ab + offA[mi]);
#pragma unroll
        for (int g = 0; g < 4; ++g)    b[g] = *(const bf16x8*)(Bb + offB[g]);
#pragma unroll
        for (int mi = 0; mi < 4; ++mi)
#pragma unroll
          for (int g = 0; g < 4; ++g)
            acc[mi][g] = __builtin_amdgcn_mfma_f32_16x16x32_bf16(
                a[mi], b[g], acc[mi][g], 0, 0, 0);
      }
      __builtin_amdgcn_s_setprio(0);
      cur = (cur == 2) ? 0 : cur + 1;
      pre = (pre == 2) ? 0 : pre + 1;
    }

    // ---- K-split merge + gate epilogue ----
    __syncthreads();   // ring reads retired before scratch overlays As/Bs[2]
    if (kh == 1) {     // upper waves: publish partial sums
#pragma unroll
      for (int mi = 0; mi < 4; ++mi)
#pragma unroll
        for (int g = 0; g < 4; ++g)
          *(f32x4*)(scr + (mi * 4 + g) * 256 + lane * 4) = acc[mi][g];
    }
    __syncthreads();
    if (kh == 0) {     // lower waves: merge + gates (4 gates of one (row,j)
                       // in the 4 g-accs, via gate-permuted WP -- proven R2+)
      const float cr = first ? c0r : cbr, cz = first ? c0z : cbz;
      const float ci = first ? c0i : cbi, ch = first ? c0h : cbh;
#pragma unroll
      for (int mi = 0; mi < 4; ++mi) {
#pragma unroll
        for (int g = 0; g < 4; ++g)
          acc[mi][g] += *(const f32x4*)(scr + (mi * 4 + g) * 256 + lane * 4);
#pragma unroll
        for (int i = 0; i < 4; ++i) {
          float rg = sigm(acc[mi][0][i] + cr);
          float zg = sigm(acc[mi][1][i] + cz);
          float ng = tanh_f(acc[mi][2][i] + ci + rg * (acc[mi][3][i] + ch));
          float h = (1.0f - zg) * ng + zg * hreg[mi][i];
          hreg[mi][i] = h;
          Hs[(twr * 64 + mi * 16 + lg * 4 + i) * 32 + twc * 16 + l15] = f2b(h);
        }
      }
    }
    __syncthreads();  // Hs complete
    {  // 16B/thread: SC1 write-through of the 128x32 slice to HH[t]
      const int row = tid >> 2, part = tid & 3;
      u32x4 v = *(const u32x4*)((char*)Hs + tid * 16);
      size_t off = (size_t)(mb * 128 + row) * 1024 + nb * 32 + part * 8;
      st16_sc1(HH + ((size_t)t << 20) + off, v);
    }

    if (t != 127) {
      // Pre-issue next step's B0,B1 (h-independent; targets Bs[0..1], which
      // do NOT alias scratch). They fly during the drain + flag/poll below.
      SSTAGE_B(0, 0)
      SSTAGE_B(1, 1)
      // FIFO: [HHstore(1) B0(2) B1(2)] -> vmcnt(4) drains the SC1 store
      asm volatile("s_waitcnt vmcnt(4)" ::: "memory");
      __syncthreads();  // all waves' HH stores at L3 before the flag
      if (tid == 0)
        __hip_atomic_store(&bar[mb * 32 + nb], (unsigned)(t + 1),
                           __ATOMIC_RELAXED, __HIP_MEMORY_SCOPE_AGENT);
      if (w == 0) {     // 32-lane parallel poll of the whole group's flags
        const unsigned tgt = (unsigned)(t + 1);
        for (;;) {
          unsigned v = __hip_atomic_load(&bar[mb * 32 + (lane & 31)],
                                         __ATOMIC_RELAXED,
                                         __HIP_MEMORY_SCOPE_AGENT);
          if (__all((int)(v >= tgt))) break;
          __builtin_amdgcn_s_sleep(1);
        }
      }
      __syncthreads();
    }
  }
#undef STAGE0
#undef SSTAGE_A
#undef SSTAGE_B
}

// ---------------- deferred out-GEMM: out = HH @ W_lin.T + b_lin ----------------
__global__ __launch_bounds__(256) void outgemm(
    const unsigned short* __restrict__ A,   // 131072 x 1024 bf16
    const unsigned short* __restrict__ Bw,  // 256 x 1024 bf16 (n-major)
    const float* __restrict__ bias,
    float* __restrict__ out)
{
  __shared__ __align__(16) unsigned short As[128 * 64];
  __shared__ __align__(16) unsigned short Bs[128 * 64];
  const int tid = threadIdx.x;
  const int w = tid >> 6, lane = tid & 63;
  const int srow = lane >> 3, schunk = (lane & 7) ^ srow;
  const int l15 = lane & 15, lg = lane >> 4;
  const int mb = blockIdx.x >> 1, nb = blockIdx.x & 1;
  const int wr = w >> 1, wc = w & 1;
  f32x4 acc[4][4] = {};
  const unsigned short* Ag = A + (size_t)(mb * 128 + w * 32) * 1024;
  const unsigned short* Bg = Bw + (size_t)(nb * 128 + w * 32) * 1024;
  for (int kt = 0; kt < 16; ++kt) {
    const int k0 = kt * 64;
    __syncthreads();
#pragma unroll
    for (int q = 0; q < 4; ++q) {
      gl_lds16(Ag + (size_t)(q * 8 + srow) * 1024 + k0 + schunk * 8,
               (char*)As + (w * 32 + q * 8) * 128);
      gl_lds16(Bg + (size_t)(q * 8 + srow) * 1024 + k0 + schunk * 8,
               (char*)Bs + (w * 32 + q * 8) * 128);
    }
    __syncthreads();
#pragma unroll
    for (int kk = 0; kk < 2; ++kk) {
      bf16x8 a[4], b[4];
#pragma unroll
      for (int mi = 0; mi < 4; ++mi) {
        int rl = wr * 64 + mi * 16 + l15;
        int slot = (kk * 4 + lg) ^ (rl & 7);
        a[mi] = *(const bf16x8*)(As + rl * 64 + slot * 8);
      }
#pragma unroll
      for (int g = 0; g < 4; ++g) {
        int cl = g * 32 + wc * 16 + l15;
        int slot = (kk * 4 + lg) ^ (cl & 7);
        b[g] = *(const bf16x8*)(Bs + cl * 64 + slot * 8);
      }
#pragma unroll
      for (int mi = 0; mi < 4; ++mi)
#pragma unroll
        for (int g = 0; g < 4; ++g)
          acc[mi][g] = __builtin_amdgcn_mfma_f32_16x16x32_bf16(
              a[mi], b[g], acc[mi][g], 0, 0, 0);
    }
  }
#pragma unroll
  for (int mi = 0; mi < 4; ++mi)
#pragma unroll
    for (int g = 0; g < 4; ++g) {
      int d = nb * 128 + g * 32 + wc * 16 + l15;
      float bb = bias[d];
#pragma unroll
      for (int i = 0; i < 4; ++i) {
        int row = mb * 128 + wr * 64 + mi * 16 + lg * 4 + i;
        out[(size_t)row * 256 + d] = acc[mi][g][i] + bb;
      }
    }
}

// ---------------- plain 128x128 GEMM (W_ih @ W_lin precompute) ----------------
__global__ __launch_bounds__(256) void gemm128(
    const unsigned short* __restrict__ A, const unsigned short* __restrict__ B,
    float* __restrict__ C, int K, int nT)
{
  __shared__ __align__(16) unsigned short As[128 * 64];
  __shared__ __align__(16) unsigned short Bs[128 * 64];
  const int tid = threadIdx.x;
  const int w = tid >> 6, lane = tid & 63;
  const int srow = lane >> 3, schunk = (lane & 7) ^ srow;
  const int l15 = lane & 15, lg = lane >> 4;
  const int mb = blockIdx.x / nT, nb = blockIdx.x % nT;
  const int wr = w >> 1, wc = w & 1;
  const int N = nT * 128;
  f32x4 acc[4][4] = {};
  const unsigned short* Ag = A + (size_t)(mb * 128 + w * 32) * K;
  const unsigned short* Bg = B + (size_t)(nb * 128 + w * 32) * K;
  for (int kt = 0; kt < (K >> 6); ++kt) {
    const int k0 = kt * 64;
    __syncthreads();
#pragma unroll
    for (int q = 0; q < 4; ++q) {
      gl_lds16(Ag + (size_t)(q * 8 + srow) * K + k0 + schunk * 8,
               (char*)As + (w * 32 + q * 8) * 128);
      gl_lds16(Bg + (size_t)(q * 8 + srow) * K + k0 + schunk * 8,
               (char*)Bs + (w * 32 + q * 8) * 128);
    }
    __syncthreads();
#pragma unroll
    for (int kk = 0; kk < 2; ++kk) {
      bf16x8 a[4], b[4];
#pragma unroll
      for (int mi = 0; mi < 4; ++mi) {
        int rl = wr * 64 + mi * 16 + l15;
        int slot = (kk * 4 + lg) ^ (rl & 7);
        a[mi] = *(const bf16x8*)(As + rl * 64 + slot * 8);
      }
#pragma unroll
      for (int g = 0; g < 4; ++g) {
        int cl = g * 32 + wc * 16 + l15;
        int slot = (kk * 4 + lg) ^ (cl & 7);
        b[g] = *(const bf16x8*)(Bs + cl * 64 + slot * 8);
      }
#pragma unroll
      for (int mi = 0; mi < 4; ++mi)
#pragma unroll
        for (int g = 0; g < 4; ++g)
          acc[mi][g] = __builtin_amdgcn_mfma_f32_16x16x32_bf16(
              a[mi], b[g], acc[mi][g], 0, 0, 0);
    }
  }
#pragma unroll
  for (int mi = 0; mi < 4; ++mi)
#pragma unroll
    for (int g = 0; g < 4; ++g)
#pragma unroll
      for (int i = 0; i < 4; ++i)
        C[(size_t)(mb * 128 + wr * 64 + mi * 16 + lg * 4 + i) * N + nb * 128 +
          g * 32 + wc * 16 + l15] = acc[mi][g][i];
}

// ---------------- small prep kernels ----------------
__global__ void castall(const float* __restrict__ x, const float* __restrict__ wih,
                        const float* __restrict__ wlin, unsigned short* __restrict__ xb,
                        unsigned short* __restrict__ wihb, unsigned short* __restrict__ wlb) {
  int i = blockIdx.x * 256 + threadIdx.x;  // grid covers 786432
  if (i < 262144) { xb[i] = f2b(x[i]); wlb[i] = f2b(wlin[i]); }
  if (i < 786432) wihb[i] = f2b(wih[i]);
}

// W_lin (256x1024) -> bf16 transpose (1024x256)
__global__ void tcast(const float* __restrict__ in, unsigned short* __restrict__ out) {
  __shared__ float t[32][33];
  int i0 = blockIdx.x * 32, d0 = blockIdx.y * 32;
  for (int r = threadIdx.y; r < 32; r += 8)
    t[r][threadIdx.x] = in[(size_t)(d0 + r) * 1024 + i0 + threadIdx.x];
  __syncthreads();
  for (int r = threadIdx.y; r < 32; r += 8)
    out[(size_t)(i0 + r) * 256 + d0 + threadIdx.x] = f2b(t[threadIdx.x][r]);
}

// Build W_big (n-major [4096][1024], gate-permuted for 64-col wave tiles)
// col layout: jt(5b) | ch(1b) | gate(2b) | c0(4b); j = jt*32 + ch*16 + c0
__global__ void asmWp(const float* __restrict__ CMT, const float* __restrict__ Whh,
                      unsigned short* __restrict__ Wp) {
  int col = blockIdx.x;
  int jt = col >> 7, L = col & 127;
  int ch = L >> 6, gate = (L >> 4) & 3, c0 = L & 15;
  int j = jt * 32 + ch * 16 + c0;
  const float* s1;
  const float* s2 = nullptr;
  if (gate == 0)      { s1 = CMT + (size_t)j * 1024;          s2 = Whh + (size_t)j * 1024; }
  else if (gate == 1) { s1 = CMT + (size_t)(1024 + j) * 1024; s2 = Whh + (size_t)(1024 + j) * 1024; }
  else if (gate == 2) { s1 = CMT + (size_t)(2048 + j) * 1024; }
  else                { s1 = Whh + (size_t)(2048 + j) * 1024; }
  unsigned short* dst = Wp + (size_t)col * 1024;
  for (int k = threadIdx.x; k < 1024; k += 256) {
    float v = s1[k] + (s2 ? s2[k] : 0.0f);
    dst[k] = f2b(v);
  }
}

// Step-0 weights: permuted W_ih.T (n-major [4096][256]), h_n group = 0
__global__ void asmWp0(const float* __restrict__ Wih, unsigned short* __restrict__ Wp0) {
  int col = blockIdx.x;
  int jt = col >> 7, L = col & 127;
  int ch = L >> 6, gate = (L >> 4) & 3, c0 = L & 15;
  int j = jt * 32 + ch * 16 + c0;
  int d = threadIdx.x;  // 256
  float v = 0.0f;
  if (gate < 3) v = Wih[(size_t)(gate * 1024 + j) * 256 + d];
  Wp0[(size_t)col * 256 + d] = f2b(v);
}

__global__ void biask(const float* __restrict__ Wih, const float* __restrict__ bih,
                      const float* __restrict__ bhh, const float* __restrict__ blin,
                      float* __restrict__ cbig, float* __restrict__ c0) {
  int j = blockIdx.x * 256 + threadIdx.x;
  if (j >= 1024) return;
  float bli[3];
  for (int g = 0; g < 3; ++g) {
    int gg = g * 1024 + j;
    float s = bih[gg];
    const float* wrow = Wih + (size_t)gg * 256;
    for (int d = 0; d < 256; ++d) s += blin[d] * wrow[d];
    bli[g] = s;
  }
  cbig[j] = bli[0] + bhh[j];
  cbig[1024 + j] = bli[1] + bhh[1024 + j];
  cbig[2048 + j] = bli[2];
  cbig[3072 + j] = bhh[2048 + j];
  c0[j] = bih[j] + bhh[j];
  c0[1024 + j] = bih[1024 + j] + bhh[1024 + j];
  c0[2048 + j] = bih[2048 + j];
  c0[3072 + j] = bhh[2048 + j];
}

// ---------------- BatchNorm ----------------
__global__ void bnstats(const float* __restrict__ o, float* __restrict__ mean,
                        float* __restrict__ rstd) {
  int t = blockIdx.x;
  int d = threadIdx.x & 255;
  int bq = threadIdx.x >> 8;  // 0..3
  const float* base = o + (size_t)t * 1024 * 256;
  float s = 0.0f, ss = 0.0f;
  for (int b = bq * 256; b < bq * 256 + 256; ++b) {
    float v = base[(size_t)b * 256 + d];
    s += v; ss += v * v;
  }
  __shared__ float S[4][256], SS[4][256];
  S[bq][d] = s; SS[bq][d] = ss;
  __syncthreads();
  if (threadIdx.x < 256) {
    float st = S[0][d] + S[1][d] + S[2][d] + S[3][d];
    float sst = SS[0][d] + SS[1][d] + SS[2][d] + SS[3][d];
    float m = st * (1.0f / 1024.0f);
    float var = sst * (1.0f / 1024.0f) - m * m;
    mean[t * 256 + d] = m;
    rstd[t * 256 + d] = rsqrtf(var + 1e-5f);
  }
}

__global__ void bnnorm(float* __restrict__ o, const float* __restrict__ mean,
                       const float* __restrict__ rstd) {
  size_t base = ((size_t)blockIdx.x * 256 + threadIdx.x) * 4;  // exact: 32768*256*4
  int t = (int)(base >> 18);
  int d = (int)(base & 255);
  float4 v = *(float4*)(o + base);
  const float* mp = mean + t * 256 + d;
  const float* rp = rstd + t * 256 + d;
  float4 r;
  r.x = (v.x - mp[0]) * rp[0];
  r.y = (v.y - mp[1]) * rp[1];
  r.z = (v.z - mp[2]) * rp[2];
  r.w = (v.w - mp[3]) * rp[3];
  *(float4*)(o + base) = r;
}

// ---------------- launch ----------------
extern "C" void kernel_launch(void* const* d_in, const int* in_sizes, int n_in,
                              void* d_out, int out_size, void* d_ws, size_t ws_size,
                              hipStream_t stream) {
  (void)in_sizes; (void)n_in; (void)out_size; (void)ws_size;
  const float* x    = (const float*)d_in[0];
  const float* h0   = (const float*)d_in[1];
  const float* Wih  = (const float*)d_in[2];
  const float* Whh  = (const float*)d_in[3];
  const float* bih  = (const float*)d_in[4];
  const float* bhh  = (const float*)d_in[5];
  const float* Wlin = (const float*)d_in[6];
  const float* blin = (const float*)d_in[7];
  float* out = (float*)d_out;

  char* ws = (char*)d_ws;
  size_t off = 0;
  auto alloc = [&](size_t bytes) {
    char* p = ws + off;
    off += (bytes + 255) & ~(size_t)255;
    return p;
  };
  unsigned short* WP   = (unsigned short*)alloc(4096ull * 1024 * 2);
  unsigned short* WP0  = (unsigned short*)alloc(4096ull * 256 * 2);
  unsigned short* WIHB = (unsigned short*)alloc(3072ull * 256 * 2);
  unsigned short* WLT  = (unsigned short*)alloc(1024ull * 256 * 2);
  unsigned short* WLB  = (unsigned short*)alloc(256ull * 1024 * 2);
  unsigned short* XB   = (unsigned short*)alloc(1024ull * 256 * 2);
  float* CMT  = (float*)alloc(3072ull * 1024 * 4);
  float* CBIG = (float*)alloc(4096 * 4);
  float* C0   = (float*)alloc(4096 * 4);
  unsigned short* HH  = (unsigned short*)alloc(128ull * 1024 * 1024 * 2);
  float* MEAN = (float*)alloc(128 * 256 * 4);
  float* RSTD = (float*)alloc(128 * 256 * 4);
  unsigned int* BAR = (unsigned int*)alloc(4096);

  (void)hipMemsetAsync(BAR, 0, 4096, stream);

  // precompute: casts, W_lin transpose, C_MT = W_ih @ W_lin, fused weights, biases
  castall<<<3072, 256, 0, stream>>>(x, Wih, Wlin, XB, WIHB, WLB);
  tcast<<<dim3(32, 8), dim3(32, 8), 0, stream>>>(Wlin, WLT);
  gemm128<<<192, 256, 0, stream>>>(WIHB, WLT, CMT, 256, 8);
  asmWp<<<4096, 256, 0, stream>>>(CMT, Whh, WP);
  asmWp0<<<4096, 256, 0, stream>>>(Wih, WP0);
  biask<<<4, 256, 0, stream>>>(Wih, bih, bhh, blin, CBIG, C0);

  // all 128 recurrence steps in one persistent kernel (256 blocks, 1/CU)
  gru_persist<<<256, 512, 0, stream>>>(XB, WP0, WP, C0, CBIG, h0, HH, BAR);

  // deferred frame outputs: out[t] = h_{t+1} @ W_lin.T + b_lin
  outgemm<<<2048, 256, 0, stream>>>(HH, WLB, blin, out);

  // BatchNorm1d (training stats), in-place on d_out
  bnstats<<<128, 1024, 0, stream>>>(out, MEAN, RSTD);
  bnnorm<<<32768, 256, 0, stream>>>(out, MEAN, RSTD);
}